// Round 9
// baseline (56.730 us; speedup 1.0000x reference)
//
#include <hip/hip_runtime.h>
#include <hip/hip_bf16.h>

// InfoNCE loss, N=4096, D=256, tau=0.5.
// loss = (1/2n)[ sum_r log(sum_{k!=r} exp(2*Z_r.Z_k)) - 2*sum_i 2*(xn_i.yn_i) ]
// Z = concat(xn, yn) row-normalized; scores in [-2,2] -> no running max needed.
// 2/tau*log2(e) folded into A-side bf16 fragments; epilogue = exp2 + add.
//
// R9: T3+T4 schedule. R7 showed the 2-phase structure serializes the pipes
// (LDS 44% + MFMA 27% + VALU 28% ~ 100% of runtime, zero overlap) because
// vmcnt(0)+barrier drains the load queue every tile. Fix per m218: BN=32
// tiles in a 4-buffer LDS ring (4x16KB = 64KB exactly -> 2 blocks/CU),
// prefetch 3 tiles ahead, counted s_waitcnt vmcnt(4) in the main loop
// (vmcnt(2)/vmcnt(0) only in the 2 tail tiles), one barrier per tile,
// T5 setprio around the MFMA cluster.

#define NROWS 8192
#define DDIM  256
#define BM    256        // rows per block = 8 waves * 32 rows
#define BN    32         // cols per LDS tile (16 KB)
#define COLSPLIT 16      // grid = 32 * 16 = 512 blocks = 2/CU exactly
#define COLS_PER (NROWS / COLSPLIT)   // 512
#define NT (COLS_PER / BN)            // 16 tiles

typedef __attribute__((ext_vector_type(8))) __bf16 bf16x8_t;
typedef __attribute__((ext_vector_type(4))) float  f32x4_t;

typedef __attribute__((address_space(1))) const void* as1_cvp;
typedef __attribute__((address_space(3))) void*       as3_vp;

#if __has_builtin(__builtin_amdgcn_exp2f)
#define EXP2F __builtin_amdgcn_exp2f
#else
#define EXP2F exp2f
#endif

#define TWO_LOG2E 2.8853900817779268f

// ---- K1: normalize rows + per-pair diag dot + zero rowsum ----
__global__ __launch_bounds__(256) void normalize_diag_kernel(
    const float* __restrict__ x, const float* __restrict__ y,
    __hip_bfloat16* __restrict__ zb, float* __restrict__ rowdiag,
    float* __restrict__ rowsum) {
  const int g = blockIdx.x * 256 + threadIdx.x;
  if (g < NROWS) rowsum[g] = 0.f;

  const int w = threadIdx.x >> 6, lane = threadIdx.x & 63;
  const int i = blockIdx.x * 4 + w;           // 0..4095
  const float4 xv = ((const float4*)(x + (size_t)i * DDIM))[lane];
  const float4 yv = ((const float4*)(y + (size_t)i * DDIM))[lane];
  float ssx = xv.x * xv.x + xv.y * xv.y + xv.z * xv.z + xv.w * xv.w;
  float ssy = yv.x * yv.x + yv.y * yv.y + yv.z * yv.z + yv.w * yv.w;
  float sxy = xv.x * yv.x + xv.y * yv.y + xv.z * yv.z + xv.w * yv.w;
  #pragma unroll
  for (int off = 32; off > 0; off >>= 1) {
    ssx += __shfl_xor(ssx, off, 64);
    ssy += __shfl_xor(ssy, off, 64);
    sxy += __shfl_xor(sxy, off, 64);
  }
  const float sclx = 1.0f / fmaxf(sqrtf(ssx), 1e-8f);
  const float scly = 1.0f / fmaxf(sqrtf(ssy), 1e-8f);
  __hip_bfloat16 px[4], py[4];
  px[0] = __float2bfloat16(xv.x * sclx); px[1] = __float2bfloat16(xv.y * sclx);
  px[2] = __float2bfloat16(xv.z * sclx); px[3] = __float2bfloat16(xv.w * sclx);
  py[0] = __float2bfloat16(yv.x * scly); py[1] = __float2bfloat16(yv.y * scly);
  py[2] = __float2bfloat16(yv.z * scly); py[3] = __float2bfloat16(yv.w * scly);
  *(short4*)(zb + (size_t)i * DDIM + lane * 4)            = *(short4*)px;
  *(short4*)(zb + (size_t)(i + 4096) * DDIM + lane * 4)   = *(short4*)py;
  if (lane == 0) rowdiag[i] = 2.0f * sxy * sclx * scly;   // target score (f32)
}

// ---- K2: fused Gram + per-row sum of exp (counted-vmcnt ring schedule) ----
__global__ __launch_bounds__(512) void gram_lse_kernel(
    const __hip_bfloat16* __restrict__ zbh, float* __restrict__ rowsum) {
  __shared__ short smem[4][BN * DDIM];  // 4 x 16 KB ring = exactly 64 KB

  const short* zs = (const short*)zbh;
  const char* zbytes = (const char*)zs;
  const int tid  = threadIdx.x;
  const int w    = tid >> 6;    // 0..7
  const int lane = tid & 63;
  const int lhi  = lane >> 4;   // 0..3
  const int llo  = lane & 15;   // 0..15
  const int i0 = (blockIdx.x >> 4) * BM;            // row-tile base (32 tiles)
  const int c0 = (blockIdx.x & 15) * COLS_PER;      // column-range base
  // rows [i0,i0+256) meet cols [c0,c0+512) on the diagonal iff:
  const bool has_diag = ((blockIdx.x >> 5) == (blockIdx.x & 15));

  // Two A-fragment sets: rows arow0 and arow0+16, full K=256, pre-scaled by
  // bf16(2*log2e) so MFMA yields score*log2(e) directly.
  const int arow0 = i0 + w * 32 + llo;
  const float TBF = __bfloat162float(__float2bfloat16(TWO_LOG2E));
  bf16x8_t afa[8], afb[8];
  #pragma unroll
  for (int ks = 0; ks < 8; ++ks) {
    afa[ks] = *(const bf16x8_t*)(zs + (size_t)arow0 * DDIM + ks * 32 + lhi * 8);
    afb[ks] = *(const bf16x8_t*)(zs + (size_t)(arow0 + 16) * DDIM + ks * 32 + lhi * 8);
    #pragma unroll
    for (int e = 0; e < 8; ++e) {
      afa[ks][e] = (__bf16)((float)afa[ks][e] * TBF);
      afb[ks][e] = (__bf16)((float)afb[ks][e] * TBF);
    }
  }

  // Staging: one gld_lds instr per thread covers 8 KB; 2 per 16 KB tile.
  // Linear LDS dest (wave-uniform base + lane*16); XOR-swizzle on global src:
  //   lds[cr*512 + slot*16 .. +16) = row (cb+cr) bytes [(slot ^ cr)*16 ..)
  int soff[2], loff[2];
  #pragma unroll
  for (int it = 0; it < 2; ++it) {
    const int o    = it * 8192 + tid * 16;
    const int cr   = o >> 9;            // 0..31
    const int slot = (o >> 4) & 31;
    soff[it] = cr * 512 + ((slot ^ cr) << 4);
    loff[it] = it * 8192 + w * 1024;    // wave-uniform dest base
  }

#define STAGE1(buf_, ct_, it_) do {                                           \
    const size_t cbase_ = (size_t)(c0 + (ct_) * BN) * 512;                    \
    __builtin_amdgcn_global_load_lds(                                         \
        (as1_cvp)(zbytes + cbase_ + (size_t)soff[it_]),                       \
        (as3_vp)((char*)smem[buf_] + loff[it_]), 16, 0, 0);                   \
  } while (0)

  float racc0[4] = {0.f, 0.f, 0.f, 0.f};
  float racc1[4] = {0.f, 0.f, 0.f, 0.f};
  const int gr0 = i0 + w * 32 + lhi * 4;   // C/D row = (lane>>4)*4 + j
  const int gr1 = gr0 + 16;

  // Prologue: prefetch tiles 0,1,2 (6 loads/thread in flight).
  #pragma unroll
  for (int t = 0; t < 3; ++t) {
    STAGE1(t, t, 0);
    STAGE1(t, t, 1);
  }

  // Per-tile body. VMSTR: counted wait -- oldest 2 loads (this tile's buf)
  // complete; younger tiles' loads stay in flight across the barrier.
#define TILE(ct_, VMSTR) do {                                                 \
    asm volatile("s_waitcnt " VMSTR ::: "memory");                            \
    __syncthreads();                                                          \
    const int cb = c0 + (ct_) * BN;                                           \
    const short* bufp = smem[(ct_) & 3];                                      \
    _Pragma("unroll")                                                         \
    for (int nt = 0; nt < 2; ++nt) {                                          \
      if ((ct_) + 3 < NT) STAGE1(((ct_) + 3) & 3, (ct_) + 3, nt);             \
      const int cr = nt * 16 + llo;                                           \
      f32x4_t acc0 = {0.f, 0.f, 0.f, 0.f};                                    \
      f32x4_t acc1 = {0.f, 0.f, 0.f, 0.f};                                    \
      __builtin_amdgcn_s_setprio(1);                                          \
      _Pragma("unroll")                                                       \
      for (int ks = 0; ks < 8; ++ks) {                                        \
        const int kg = ks * 4 + lhi;                                          \
        const bf16x8_t bfrag = *(const bf16x8_t*)(                            \
            (const char*)bufp + cr * 512 + ((kg ^ cr) << 4));                 \
        acc0 = __builtin_amdgcn_mfma_f32_16x16x32_bf16(afa[ks], bfrag, acc0, 0, 0, 0); \
        acc1 = __builtin_amdgcn_mfma_f32_16x16x32_bf16(afb[ks], bfrag, acc1, 0, 0, 0); \
      }                                                                       \
      __builtin_amdgcn_s_setprio(0);                                          \
      if (has_diag) {                                                         \
        const int gc = cb + cr;                                               \
        _Pragma("unroll")                                                     \
        for (int j = 0; j < 4; ++j) {                                         \
          racc0[j] += ((gr0 + j) != gc) ? EXP2F(acc0[j]) : 0.f;               \
          racc1[j] += ((gr1 + j) != gc) ? EXP2F(acc1[j]) : 0.f;               \
        }                                                                     \
      } else {                                                                \
        _Pragma("unroll")                                                     \
        for (int j = 0; j < 4; ++j) {                                         \
          racc0[j] += EXP2F(acc0[j]);                                         \
          racc1[j] += EXP2F(acc1[j]);                                         \
        }                                                                     \
      }                                                                       \
    }                                                                         \
  } while (0)

  for (int ct = 0; ct < NT - 2; ++ct) TILE(ct, "vmcnt(4)");
  TILE(NT - 2, "vmcnt(2)");
  TILE(NT - 1, "vmcnt(0)");
#undef TILE
#undef STAGE1

  // Per-row partial sums -> global rowsum (16 adds per row address total).
  #pragma unroll
  for (int j = 0; j < 4; ++j) {
    float v0 = racc0[j], v1 = racc1[j];
    v0 += __shfl_xor(v0, 1, 16); v1 += __shfl_xor(v1, 1, 16);
    v0 += __shfl_xor(v0, 2, 16); v1 += __shfl_xor(v1, 2, 16);
    v0 += __shfl_xor(v0, 4, 16); v1 += __shfl_xor(v1, 4, 16);
    v0 += __shfl_xor(v0, 8, 16); v1 += __shfl_xor(v1, 8, 16);
    if (llo == 0) {
      atomicAdd(&rowsum[gr0 + j], v0);
      atomicAdd(&rowsum[gr1 + j], v1);
    }
  }
}

// ------- K3: loss = (sum_r log(rowsum_r) - 2*sum_i rowdiag_i) / 2n -------
__global__ __launch_bounds__(256) void finalize_kernel(
    const float* __restrict__ rowsum, const float* __restrict__ rowdiag,
    float* __restrict__ out) {
  const int t = threadIdx.x;
  float s = 0.f;
  for (int r4 = t; r4 < NROWS / 4; r4 += 256) {
    const float4 v = ((const float4*)rowsum)[r4];
    s += __logf(v.x) + __logf(v.y) + __logf(v.z) + __logf(v.w);
  }
  for (int i4 = t; i4 < 4096 / 4; i4 += 256) {
    const float4 d = ((const float4*)rowdiag)[i4];
    s -= 2.0f * (d.x + d.y + d.z + d.w);
  }
  #pragma unroll
  for (int off = 32; off > 0; off >>= 1) s += __shfl_xor(s, off, 64);
  __shared__ float wsum[4];
  const int w = t >> 6, lane = t & 63;
  if (lane == 0) wsum[w] = s;
  __syncthreads();
  if (t == 0) out[0] = (wsum[0] + wsum[1] + wsum[2] + wsum[3]) / (float)NROWS;
}

extern "C" void kernel_launch(void* const* d_in, const int* in_sizes, int n_in,
                              void* d_out, int out_size, void* d_ws, size_t ws_size,
                              hipStream_t stream) {
  const float* x = (const float*)d_in[0];
  const float* y = (const float*)d_in[1];
  float* out = (float*)d_out;

  char* ws = (char*)d_ws;
  __hip_bfloat16* zb = (__hip_bfloat16*)ws;                       // 4 MB
  float* rowsum  = (float*)(ws + (size_t)NROWS * DDIM * 2);       // 32 KB
  float* rowdiag = rowsum + NROWS;                                // 16 KB

  normalize_diag_kernel<<<1024, 256, 0, stream>>>(x, y, zb, rowdiag, rowsum);
  gram_lse_kernel<<<512, 512, 0, stream>>>(zb, rowsum);
  finalize_kernel<<<1, 256, 0, stream>>>(rowsum, rowdiag, out);
}